// Round 5
// baseline (95.640 us; speedup 1.0000x reference)
//
#include <hip/hip_runtime.h>
#include <math.h>

#define BB   8
#define NN   96
#define DD   16
#define H0D  50
#define H1D  50
#define OUTD 64
#define XP   17
#define MAXC 32

typedef unsigned long long u64;

// W1: (51,50): rows 0-15 Wxi, 16-31 Wxj, 32-47 Wxk, 48 w_ij, 49 w_jk, 50 w_ik
// W2: (83,50): rows 0-15 xi, 16-31 xj, 32 dis, 33-82 m3
// W3: (66,64)

__global__ __launch_bounds__(256) void sgc5(
    const float* __restrict__ x, const float* __restrict__ adj,
    const float* __restrict__ W1, const float* __restrict__ b1,
    const float* __restrict__ W2, const float* __restrict__ b2,
    const float* __restrict__ W3, const float* __restrict__ b3,
    float* __restrict__ out)
{
    const int b = blockIdx.x / NN, i = blockIdx.x % NN;
    const int tid = threadIdx.x, wv = tid >> 6, lane = tid & 63;

    __shared__ float sx[NN * XP];          // x[b], padded
    __shared__ float sW1[51 * H0D];        // full W1
    __shared__ float srows[MAXC * NN];     // neighbor adj rows (transient)
    __shared__ float sdisI[NN];            // dis row i
    __shared__ int   nbrs[NN];
    __shared__ u64   smasks[MAXC][2];
    __shared__ u64   smi[2];
    __shared__ float sA[H0D];
    __shared__ float sP[MAXC * H0D];
    __shared__ float snxc[MAXC * DD];
    __shared__ float spjk[MAXC * 8], spik[MAXC * 8];
    __shared__ float sdegc[MAXC], ssdjkc[MAXC], ssdikc[MAXC];
    __shared__ float smsum[H0D], sm2[H1D], snxi[DD];
    __shared__ float sdummy[64];
    __shared__ float ssdjki_s;
    __shared__ int   scnt;

    float b1v = 0.f, b2v = 0.f, b3v = 0.f;

    // ---------- phase 0: issue ALL global loads up front ----------
    const float4* x4 = (const float4*)(x + (size_t)b * NN * DD);
    for (int t = tid; t < NN * DD / 4; t += 256) {
        float4 v = x4[t];
        float* p = &sx[(t >> 2) * XP + (t & 3) * 4];
        p[0] = v.x; p[1] = v.y; p[2] = v.z; p[3] = v.w;
    }
    const float2* w12 = (const float2*)W1;
    for (int t = tid; t < 51 * H0D / 2; t += 256) {
        float2 v = w12[t];
        sW1[2 * t] = v.x; sW1[2 * t + 1] = v.y;
    }
    if (wv == 0) {   // adj row i -> mask + compact neighbor list
        const float* arow = adj + ((size_t)b * NN + i) * NN;
        float a0 = arow[lane];
        float a1 = (lane < 32) ? arow[64 + lane] : 0.f;
        u64 m0 = __ballot(a0 != 0.f);
        u64 m1 = __ballot(a1 != 0.f);
        int c0n = __popcll(m0);
        if ((m0 >> lane) & 1)
            nbrs[__popcll(m0 & ((1ull << lane) - 1))] = lane;
        if (lane < 32 && ((m1 >> lane) & 1))
            nbrs[c0n + __popcll(m1 & ((1ull << lane) - 1))] = 64 + lane;
        if (lane == 0) { smi[0] = m0; smi[1] = m1; scnt = c0n + __popcll(m1); }
    }
    if (tid < H0D)  b1v = b1[tid];
    if (tid < H1D)  b2v = b2[tid];
    if (tid < OUTD) b3v = b3[tid];
    if (tid < H0D)  smsum[tid] = 0.f;
    {   // warm W2/W3 into L2 (sink is never read)
        float ws = 0.f;
        const float2* w22 = (const float2*)W2;
        for (int t = tid; t < 83 * H1D / 2; t += 256) { float2 v = w22[t]; ws += v.x + v.y; }
        const float4* w34 = (const float4*)W3;
        for (int t = tid; t < 66 * OUTD / 4; t += 256) { float4 v = w34[t]; ws += v.x + v.y + v.z + v.w; }
        sdummy[lane] = ws;
    }
    __syncthreads();

    // ---------- phase 1: dis row i + A_i (LDS only) ----------
    if (tid < NN) {
        const float* xi = &sx[i * XP];
        const float* xk = &sx[tid * XP];
        float s = 1e-10f;
        #pragma unroll
        for (int d = 0; d < DD; ++d) { float t = xi[d] - xk[d]; s += t * t; }
        sdisI[tid] = sqrtf(s);
    } else if (tid < NN + H0D) {
        int h = tid - NN;
        float s = 0.f;
        #pragma unroll
        for (int d = 0; d < DD; ++d) s += sx[i * XP + d] * sW1[d * H0D + h];
        sA[h] = s;
    }
    __syncthreads();

    // i-row extras (read in layer 2, many syncs later)
    if (tid < DD) {
        u64 m0 = smi[0], m1 = smi[1];
        float s = 0.f;
        while (m0) { int k = __ffsll(m0) - 1;      m0 &= m0 - 1; s += sx[k * XP + tid]; }
        while (m1) { int k = 64 + __ffsll(m1) - 1; m1 &= m1 - 1; s += sx[k * XP + tid]; }
        snxi[tid] = s;
    } else if (tid == DD) {
        u64 m0 = smi[0], m1 = smi[1];
        float s = 0.f;
        while (m0) { int k = __ffsll(m0) - 1;      m0 &= m0 - 1; s += sdisI[k]; }
        while (m1) { int k = 64 + __ffsll(m1) - 1; m1 &= m1 - 1; s += sdisI[k]; }
        ssdjki_s = s;
    }

    const int cnt = scnt;
    const float degi = (float)cnt;

    for (int c0 = 0; c0 < cnt; c0 += MAXC) {
        const int cc = min(MAXC, cnt - c0);

        // ---------- phase 2: neighbor adj rows -> LDS (L2-warm via siblings) ----------
        for (int t = tid; t < cc * 24; t += 256) {
            int c = t / 24, f = t % 24;
            const float4 v = *(const float4*)(adj + ((size_t)b * NN + nbrs[c0 + c]) * NN + f * 4);
            float* p = &srows[c * NN + f * 4];
            p[0] = v.x; p[1] = v.y; p[2] = v.z; p[3] = v.w;
        }
        __syncthreads();
        // masks + deg per neighbor
        for (int c = wv; c < cc; c += 4) {
            float v0 = srows[c * NN + lane];
            float v1 = (lane < 32) ? srows[c * NN + 64 + lane] : 0.f;
            u64 m0 = __ballot(v0 != 0.f);
            u64 m1 = __ballot(v1 != 0.f);
            if (lane == 0) {
                smasks[c][0] = m0; smasks[c][1] = m1;
                sdegc[c] = (float)(__popcll(m0) + __popcll(m1));
            }
        }
        __syncthreads();

        // ---------- phase 3a: sd_jk / sd_ik partials, (c, 12-bit seg) ----------
        {
            int c = tid >> 3, seg = tid & 7;
            if (c < cc) {
                u64 m0 = smasks[c][0], m1 = smasks[c][1];
                int s = seg * 12;
                u64 wnd;
                if (s < 64) {
                    wnd = m0 >> s;
                    if (s) wnd |= (m1 << (64 - s));
                } else {
                    wnd = m1 >> (s - 64);
                }
                wnd &= 0xFFFull;
                const float* xj = &sx[nbrs[c0 + c] * XP];
                float pjk = 0.f, pik = 0.f;
                while (wnd) {
                    int k = s + __ffsll(wnd) - 1;
                    wnd &= wnd - 1;
                    const float* xk = &sx[k * XP];
                    float ss = 1e-10f;
                    #pragma unroll
                    for (int d = 0; d < DD; ++d) { float t = xj[d] - xk[d]; ss += t * t; }
                    pjk += sqrtf(ss);
                    pik += sdisI[k];
                }
                spjk[c * 8 + seg] = pjk;
                spik[c * 8 + seg] = pik;
            }
        }
        __syncthreads();

        // ---------- phase 3b: reduce partials + nx per neighbor ----------
        if (tid < 2 * MAXC) {
            int c = tid >> 1;
            if (c < cc) {
                const float* p = (tid & 1) ? &spjk[c * 8] : &spik[c * 8];
                float s = p[0] + p[1] + p[2] + p[3] + p[4] + p[5] + p[6] + p[7];
                if (tid & 1) ssdjkc[c] = s; else ssdikc[c] = s;
            }
        }
        for (int u = tid; u < cc * DD; u += 256) {
            int c = u >> 4, d = u & 15;
            u64 m0 = smasks[c][0], m1 = smasks[c][1];
            float s = 0.f;
            while (m0) { int k = __ffsll(m0) - 1;      m0 &= m0 - 1; s += sx[k * XP + d]; }
            while (m1) { int k = 64 + __ffsll(m1) - 1; m1 &= m1 - 1; s += sx[k * XP + d]; }
            snxc[u] = s;
        }
        __syncthreads();

        // ---------- phase 4: P_c[h] = deg_c*(x_j@Wxj)[h] + (nx_c@Wxk)[h] ----------
        #pragma unroll
        for (int r = 0; r < 7; ++r) {
            int u = r * 256 + tid;
            int c = u / H0D, h = u - c * H0D;
            if (c < cc) {
                const float* xj = &sx[nbrs[c0 + c] * XP];
                const float* nx = &snxc[c * DD];
                float bm = 0.f, sc = 0.f;
                #pragma unroll
                for (int d = 0; d < DD; ++d) {
                    bm += xj[d] * sW1[(DD + d) * H0D + h];
                    sc += nx[d] * sW1[(2 * DD + d) * H0D + h];
                }
                sP[c * H0D + h] = sdegc[c] * bm + sc;
            }
        }
        __syncthreads();

        // ---------- phase 5: msum accumulate over neighbors ----------
        if (tid < H0D) {
            const int h = tid;
            const float abv = sA[h] + b1v;
            const float wij = sW1[(3 * DD + 0) * H0D + h];
            const float wjk = sW1[(3 * DD + 1) * H0D + h];
            const float wik = sW1[(3 * DD + 2) * H0D + h];
            float acc = 0.f;
            for (int c = 0; c < cc; ++c) {
                float S = sdegc[c] * (abv + sdisI[nbrs[c0 + c]] * wij)
                        + sP[c * H0D + h] + ssdjkc[c] * wjk + ssdikc[c] * wik;
                acc += (S >= 0.f) ? S : 0.05f * S;
            }
            smsum[h] += acc;
        }
        __syncthreads();
    }

    // ---------- phase 6: layer 2 (W2 L2-warm) ----------
    if (tid < H1D) {
        const int h = tid;
        float s = degi * b2v;
        #pragma unroll
        for (int d = 0; d < DD; ++d)
            s += degi * sx[i * XP + d] * W2[d * H1D + h]
               + snxi[d] * W2[(DD + d) * H1D + h];
        s += ssdjki_s * W2[(2 * DD) * H1D + h];
        #pragma unroll
        for (int c = 0; c < H0D; ++c)
            s += smsum[c] * W2[(2 * DD + 1 + c) * H1D + h];
        sm2[h] = (s >= 0.f) ? s : 0.05f * s;
    }
    __syncthreads();

    // ---------- phase 7: layer 3 + store (W3 L2-warm) ----------
    if (tid < OUTD) {
        const int o = tid;
        float s = b3v;
        #pragma unroll
        for (int d = 0; d < DD; ++d) s += sx[i * XP + d] * W3[d * OUTD + o];
        #pragma unroll
        for (int h = 0; h < H1D; ++h) s += sm2[h] * W3[(DD + h) * OUTD + o];
        s = (s >= 0.f) ? s : 0.05f * s;
        out[((size_t)b * NN + i) * OUTD + o] = s;
    }
}

extern "C" void kernel_launch(void* const* d_in, const int* in_sizes, int n_in,
                              void* d_out, int out_size, void* d_ws, size_t ws_size,
                              hipStream_t stream) {
    const float* x   = (const float*)d_in[0];
    const float* adj = (const float*)d_in[1];
    const float* W1  = (const float*)d_in[2];
    const float* b1  = (const float*)d_in[3];
    const float* W2  = (const float*)d_in[4];
    const float* b2  = (const float*)d_in[5];
    const float* W3  = (const float*)d_in[6];
    const float* b3  = (const float*)d_in[7];
    float* out = (float*)d_out;

    sgc5<<<BB * NN, 256, 0, stream>>>(x, adj, W1, b1, W2, b2, W3, b3, out);
}

// Round 6
// 83.856 us; speedup vs baseline: 1.1405x; 1.1405x over previous
//
#include <hip/hip_runtime.h>
#include <math.h>

#define BB   8
#define NN   96
#define DD   16
#define H0D  50
#define H1D  50
#define OUTD 64
#define XP   17

typedef unsigned long long u64;

// W1: (51,50): rows 0-15 Wxi, 16-31 Wxj, 32-47 Wxk, 48 w_ij, 49 w_jk, 50 w_ik
// W2: (83,50): rows 0-15 xi, 16-31 xj, 32 dis, 33-82 m3
// W3: (66,64)

__device__ __forceinline__ float wave_reduce_sum(float v) {
    #pragma unroll
    for (int off = 1; off < 64; off <<= 1)
        v += __shfl_xor(v, off, 64);
    return v;
}

// ---- kernel A: one wave per (b, j) -----------------------------------------
__global__ __launch_bounds__(64) void kA(
    const float* __restrict__ x, const float* __restrict__ adj,
    const float* __restrict__ W1,
    float* __restrict__ disws, u64* __restrict__ maskws,
    float* __restrict__ degws, float* __restrict__ sdjkws,
    float* __restrict__ nxws, float* __restrict__ APws)
{
    const int b = blockIdx.x / NN, j = blockIdx.x % NN;
    const int lane = threadIdx.x;
    __shared__ float sx[NN * XP];
    __shared__ float snx[DD];

    // stage x[b] (float4, coalesced)
    const float4* x4 = (const float4*)(x + (size_t)b * NN * DD);
    #pragma unroll
    for (int t = lane; t < NN * DD / 4; t += 64) {
        float4 v = x4[t];
        int row = t >> 2, d = (t & 3) * 4;
        float* p = &sx[row * XP + d];
        p[0] = v.x; p[1] = v.y; p[2] = v.z; p[3] = v.w;
    }
    // adjacency bitmask for row j (adj values are exactly 0/1)
    const float* arow = adj + ((size_t)b * NN + j) * NN;
    float a0 = arow[lane];
    float a1 = (lane < NN - 64) ? arow[64 + lane] : 0.f;
    u64 m0 = __ballot(a0 != 0.f);
    u64 m1 = __ballot(a1 != 0.f);
    __syncthreads();

    // dis row j (lane = k, two rounds)
    const float* xj = &sx[j * XP];
    float d0, d1 = 0.f;
    {
        float s = 1e-10f;
        const float* xk = &sx[lane * XP];
        #pragma unroll
        for (int d = 0; d < DD; ++d) { float t = xj[d] - xk[d]; s += t * t; }
        d0 = sqrtf(s);
    }
    if (lane < NN - 64) {
        float s = 1e-10f;
        const float* xk = &sx[(64 + lane) * XP];
        #pragma unroll
        for (int d = 0; d < DD; ++d) { float t = xj[d] - xk[d]; s += t * t; }
        d1 = sqrtf(s);
    }
    float* drow = disws + ((size_t)b * NN + j) * NN;
    drow[lane] = d0;
    if (lane < NN - 64) drow[64 + lane] = d1;

    float deg = (float)(__popcll(m0) + __popcll(m1));
    float part = (((m0 >> lane) & 1) ? d0 : 0.f)
               + ((lane < 32 && ((m1 >> lane) & 1)) ? d1 : 0.f);
    float sdjk = wave_reduce_sum(part);
    if (lane == 0) {
        degws[b * NN + j]  = deg;
        sdjkws[b * NN + j] = sdjk;
        maskws[(b * NN + j) * 2 + 0] = m0;
        maskws[(b * NN + j) * 2 + 1] = m1;
    }

    // nx_j[d] = sum_{k in nbr(j)} x_k[d]; lane = d + 16*chunk, 24 k's per chunk
    {
        int c = lane >> 4, d = lane & 15;
        unsigned sm;
        if (c == 0)      sm = (unsigned)(m0 & 0xFFFFFFu);
        else if (c == 1) sm = (unsigned)((m0 >> 24) & 0xFFFFFFu);
        else if (c == 2) sm = (unsigned)((m0 >> 48) & 0xFFFFu) | ((unsigned)(m1 & 0xFFu) << 16);
        else             sm = (unsigned)((m1 >> 8) & 0xFFFFFFu);
        float s = 0.f;
        int base = c * 24;
        while (sm) {
            int k = base + __ffs(sm) - 1;
            sm &= sm - 1;
            s += sx[k * XP + d];
        }
        s += __shfl_xor(s, 16, 64);
        s += __shfl_xor(s, 32, 64);
        if (lane < DD) {
            snx[lane] = s;
            nxws[(b * NN + j) * DD + lane] = s;
        }
    }
    __syncthreads();

    // A_j[h] = x_j@Wxi;  P_j[h] = deg_j*(x_j@Wxj)[h] + (nx_j@Wxk)[h]
    if (lane < H0D) {
        float a = 0.f, bm = 0.f, sc = 0.f;
        #pragma unroll
        for (int d = 0; d < DD; ++d) {
            float xv = xj[d];
            a  += xv * W1[d * H0D + lane];
            bm += xv * W1[(DD + d) * H0D + lane];
            sc += snx[d] * W1[(2 * DD + d) * H0D + lane];
        }
        float* ap = APws + ((size_t)b * NN + j) * 128;
        ap[lane]      = a;
        ap[64 + lane] = deg * bm + sc;
    }
}

// ---- kernel B: one wave per (b, i) -----------------------------------------
__global__ __launch_bounds__(64) void kB(
    const float* __restrict__ x,
    const float* __restrict__ W1, const float* __restrict__ b1,
    const float* __restrict__ W2, const float* __restrict__ b2,
    const float* __restrict__ W3, const float* __restrict__ b3,
    const float* __restrict__ disws, const u64* __restrict__ maskws,
    const float* __restrict__ degws, const float* __restrict__ sdjkws,
    const float* __restrict__ nxws, const float* __restrict__ APws,
    float* __restrict__ out)
{
    const int b = blockIdx.x / NN, i = blockIdx.x % NN;
    const int lane = threadIdx.x;
    __shared__ u64 sm0[NN], sm1[NN];
    __shared__ float sdis[NN], sdeg[NN], ssdjk[NN], ssdik[NN];
    __shared__ float smsum[H0D], sm2[H1D], sxi[DD], snxi[DD];

    const ulonglong2* mp = (const ulonglong2*)(maskws + (size_t)b * NN * 2);
    #pragma unroll
    for (int t = lane; t < NN; t += 64) {
        ulonglong2 m = mp[t];
        sm0[t] = m.x; sm1[t] = m.y;
    }
    const float* drow = disws + ((size_t)b * NN + i) * NN;
    sdis[lane] = drow[lane];
    if (lane < 32) sdis[64 + lane] = drow[64 + lane];
    sdeg[lane] = degws[b * NN + lane];
    if (lane < 32) sdeg[64 + lane] = degws[b * NN + 64 + lane];
    ssdjk[lane] = sdjkws[b * NN + lane];
    if (lane < 32) ssdjk[64 + lane] = sdjkws[b * NN + 64 + lane];
    if (lane < DD) {
        sxi[lane]  = x[((size_t)b * NN + i) * DD + lane];
        snxi[lane] = nxws[(b * NN + i) * DD + lane];
    }
    __syncthreads();

    // sd_ik[i,j] = sum_{k in nbr(j)} dis[i,k]; lane = j (two rounds)
    {
        u64 mm0 = sm0[lane], mm1 = sm1[lane];
        float s = 0.f;
        while (mm0) { int k = __ffsll(mm0) - 1;      mm0 &= mm0 - 1; s += sdis[k]; }
        while (mm1) { int k = 64 + __ffsll(mm1) - 1; mm1 &= mm1 - 1; s += sdis[k]; }
        ssdik[lane] = s;
        if (lane < 32) {
            int j = 64 + lane;
            u64 n0 = sm0[j], n1 = sm1[j];
            float t = 0.f;
            while (n0) { int k = __ffsll(n0) - 1;      n0 &= n0 - 1; t += sdis[k]; }
            while (n1) { int k = 64 + __ffsll(n1) - 1; n1 &= n1 - 1; t += sdis[k]; }
            ssdik[j] = t;
        }
    }
    __syncthreads();

    // neighbor accumulation: lane = channel h, wave-uniform mask walk
    {
        const int h = (lane < H0D) ? lane : 0;
        float ab  = APws[((size_t)b * NN + i) * 128 + h] + b1[h];
        float wij = W1[(3 * DD + 0) * H0D + h];
        float wjk = W1[(3 * DD + 1) * H0D + h];
        float wik = W1[(3 * DD + 2) * H0D + h];
        float msum = 0.f;
        u64 mm = sm0[i]; int base = 0;
        for (int half = 0; half < 2; ++half) {
            while (mm) {
                int j = base + __ffsll(mm) - 1;
                mm &= mm - 1;
                float S = sdeg[j] * (ab + sdis[j] * wij)
                        + APws[((size_t)b * NN + j) * 128 + 64 + h]
                        + ssdjk[j] * wjk + ssdik[j] * wik;
                msum += (S >= 0.f) ? S : 0.05f * S;
            }
            mm = sm1[i]; base = 64;
        }
        if (lane < H0D) smsum[lane] = msum;
    }
    __syncthreads();

    // layer 2
    const float degi = sdeg[i], sdjki = ssdjk[i];
    if (lane < H1D) {
        float s = degi * b2[lane];
        #pragma unroll
        for (int d = 0; d < DD; ++d)
            s += degi * sxi[d] * W2[d * H1D + lane]
               + snxi[d] * W2[(DD + d) * H1D + lane];
        s += sdjki * W2[(2 * DD) * H1D + lane];
        for (int c = 0; c < H0D; ++c)
            s += smsum[c] * W2[(2 * DD + 1 + c) * H1D + lane];
        sm2[lane] = (s >= 0.f) ? s : 0.05f * s;
    }
    __syncthreads();

    // layer 3 + store (lane = output channel)
    {
        float s = b3[lane];
        #pragma unroll
        for (int d = 0; d < DD; ++d) s += sxi[d] * W3[d * OUTD + lane];
        for (int h = 0; h < H1D; ++h) s += sm2[h] * W3[(DD + h) * OUTD + lane];
        s = (s >= 0.f) ? s : 0.05f * s;
        out[((size_t)b * NN + i) * OUTD + lane] = s;
    }
}

extern "C" void kernel_launch(void* const* d_in, const int* in_sizes, int n_in,
                              void* d_out, int out_size, void* d_ws, size_t ws_size,
                              hipStream_t stream) {
    const float* x   = (const float*)d_in[0];
    const float* adj = (const float*)d_in[1];
    const float* W1  = (const float*)d_in[2];
    const float* b1  = (const float*)d_in[3];
    const float* W2  = (const float*)d_in[4];
    const float* b2  = (const float*)d_in[5];
    const float* W3  = (const float*)d_in[6];
    const float* b3  = (const float*)d_in[7];
    float* out = (float*)d_out;

    // ws layout: masks (u64, 8B-aligned) first, then floats
    u64*   maskws = (u64*)d_ws;                        // 8*96*2 u64 = 12288 B
    float* fbase  = (float*)((char*)d_ws + BB * NN * 2 * sizeof(u64));
    float* disws  = fbase;                             // 8*96*96
    float* degws  = disws + BB * NN * NN;              // 768
    float* sdjkws = degws + BB * NN;                   // 768
    float* nxws   = sdjkws + BB * NN;                  // 8*96*16
    float* APws   = nxws + BB * NN * DD;               // 8*96*128

    kA<<<BB * NN, 64, 0, stream>>>(x, adj, W1, disws, maskws, degws, sdjkws, nxws, APws);
    kB<<<BB * NN, 64, 0, stream>>>(x, W1, b1, W2, b2, W3, b3,
                                   disws, maskws, degws, sdjkws, nxws, APws, out);
}